// Round 1
// baseline (458.300 us; speedup 1.0000x reference)
//
#include <hip/hip_runtime.h>

#define MAT_N 256
#define TPB   1024
#define ITERS 20

// One block per 256x256 matrix. 1024 threads = 32x32 grid of 8x8 register tiles.
// Sinkhorn in multiplicative domain: E = exp(x) held in registers (64 VGPR/thread),
// f/g scaling vectors + reduction partials in LDS.
__global__ __launch_bounds__(TPB, 4) void sinkhorn_kernel(
    const float* __restrict__ x, float* __restrict__ out)
{
    const int t    = threadIdx.x;
    const int tR   = t >> 5;        // 0..31 tile row
    const int tC   = t & 31;        // 0..31 tile col
    const int row0 = tR << 3;
    const int col0 = tC << 3;

    const float* __restrict__ xm = x   + (size_t)blockIdx.x * (MAT_N * MAT_N);
    float* __restrict__       om = out + (size_t)blockIdx.x * (MAT_N * MAT_N);

    __shared__ float part[32][MAT_N + 8];   // stride 264 floats (1056 B, 16B-aligned rows)
    __shared__ float fvec[MAT_N];
    __shared__ float gvec[MAT_N];

    // ---- load tile, E = exp(x) (computed once) ----
    float E[8][8];
#pragma unroll
    for (int l = 0; l < 8; ++l) {
        const float* rp = xm + (row0 + l) * MAT_N + col0;
        float4 a = *(const float4*)(rp);
        float4 b = *(const float4*)(rp + 4);
        E[l][0] = __expf(a.x); E[l][1] = __expf(a.y);
        E[l][2] = __expf(a.z); E[l][3] = __expf(a.w);
        E[l][4] = __expf(b.x); E[l][5] = __expf(b.y);
        E[l][6] = __expf(b.z); E[l][7] = __expf(b.w);
    }
    if (t < MAT_N) fvec[t] = 1.0f;
    __syncthreads();

    for (int it = 0; it < ITERS; ++it) {
        // ---------- column pass: g = 1 / (E^T f) ----------
        float4 f0 = *(const float4*)&fvec[row0];
        float4 f1 = *(const float4*)&fvec[row0 + 4];
        float fl[8] = {f0.x, f0.y, f0.z, f0.w, f1.x, f1.y, f1.z, f1.w};
        float p[8];
#pragma unroll
        for (int k = 0; k < 8; ++k) p[k] = E[0][k] * fl[0];
#pragma unroll
        for (int l = 1; l < 8; ++l)
#pragma unroll
            for (int k = 0; k < 8; ++k) p[k] += E[l][k] * fl[l];
        *(float4*)&part[tR][col0]     = make_float4(p[0], p[1], p[2], p[3]);
        *(float4*)&part[tR][col0 + 4] = make_float4(p[4], p[5], p[6], p[7]);
        __syncthreads();
        if (t < MAT_N) {
            float s = 0.0f;
#pragma unroll
            for (int R = 0; R < 32; ++R) s += part[R][t];
            gvec[t] = 1.0f / s;
        }
        __syncthreads();

        // ---------- row pass: f = 1 / (E g) ----------
        float4 g0 = *(const float4*)&gvec[col0];
        float4 g1 = *(const float4*)&gvec[col0 + 4];
        float gl[8] = {g0.x, g0.y, g0.z, g0.w, g1.x, g1.y, g1.z, g1.w};
        float q[8];
#pragma unroll
        for (int l = 0; l < 8; ++l) {
            float s = E[l][0] * gl[0];
#pragma unroll
            for (int k = 1; k < 8; ++k) s += E[l][k] * gl[k];
            q[l] = s;
        }
        *(float4*)&part[tC][row0]     = make_float4(q[0], q[1], q[2], q[3]);
        *(float4*)&part[tC][row0 + 4] = make_float4(q[4], q[5], q[6], q[7]);
        __syncthreads();
        if (t < MAT_N) {
            float s = 0.0f;
#pragma unroll
            for (int C = 0; C < 32; ++C) s += part[C][t];
            fvec[t] = 1.0f / s;
        }
        __syncthreads();
    }

    // ---------- output: out = E * f[row] * g[col] ----------
    float4 f0 = *(const float4*)&fvec[row0];
    float4 f1 = *(const float4*)&fvec[row0 + 4];
    float fl[8] = {f0.x, f0.y, f0.z, f0.w, f1.x, f1.y, f1.z, f1.w};
    float4 g0 = *(const float4*)&gvec[col0];
    float4 g1 = *(const float4*)&gvec[col0 + 4];
    float gl[8] = {g0.x, g0.y, g0.z, g0.w, g1.x, g1.y, g1.z, g1.w};
#pragma unroll
    for (int l = 0; l < 8; ++l) {
        float fr = fl[l];
        float* rp = om + (row0 + l) * MAT_N + col0;
        *(float4*)(rp)     = make_float4(E[l][0] * fr * gl[0], E[l][1] * fr * gl[1],
                                         E[l][2] * fr * gl[2], E[l][3] * fr * gl[3]);
        *(float4*)(rp + 4) = make_float4(E[l][4] * fr * gl[4], E[l][5] * fr * gl[5],
                                         E[l][6] * fr * gl[6], E[l][7] * fr * gl[7]);
    }
}

extern "C" void kernel_launch(void* const* d_in, const int* in_sizes, int n_in,
                              void* d_out, int out_size, void* d_ws, size_t ws_size,
                              hipStream_t stream) {
    const float* x = (const float*)d_in[0];
    float* out = (float*)d_out;
    const int nmat = in_sizes[0] / (MAT_N * MAT_N);   // 64*8 = 512
    sinkhorn_kernel<<<nmat, TPB, 0, stream>>>(x, out);
}

// Round 2
// 366.246 us; speedup vs baseline: 1.2513x; 1.2513x over previous
//
#include <hip/hip_runtime.h>

#define MAT_N 256
#define TPB   1024
#define ITERS 20

// One block per 256x256 matrix; 1024 threads = 32x32 grid of 8x8 register tiles.
// Multiplicative-domain Sinkhorn: E = exp(x) held in VGPRs (64 regs/thread).
// Row pass: pure in-wave shuffle butterfly (f never leaves registers).
// Col pass: shfl_xor(32) pair-reduce -> 16 LDS partial rows (bank-swizzled) -> 2 barriers/iter.
__global__ __launch_bounds__(TPB) void sinkhorn_kernel(
    const float* __restrict__ x, float* __restrict__ out)
{
    const int t    = threadIdx.x;
    const int tR   = t >> 5;          // 0..31 tile row
    const int tC   = t & 31;          // 0..31 tile col
    const int row0 = tR << 3;
    const int col0 = tC << 3;
    const int w    = t >> 6;          // wave index 0..15
    const int rot  = (tC >> 2) & 7;   // bank-swizzle rotation for partial writes

    const float* __restrict__ xm = x   + (size_t)blockIdx.x * (MAT_N * MAT_N);
    float* __restrict__       om = out + (size_t)blockIdx.x * (MAT_N * MAT_N);

    __shared__ float part[16][MAT_N];   // pair-reduced column partials, swizzled
    __shared__ float gvec[MAT_N];

    // ---- load tile, E = exp(x) ----
    float E[8][8];
#pragma unroll
    for (int l = 0; l < 8; ++l) {
        const float* rp = xm + (row0 + l) * MAT_N + col0;
        float4 a = *(const float4*)(rp);
        float4 b = *(const float4*)(rp + 4);
        E[l][0] = __expf(a.x); E[l][1] = __expf(a.y);
        E[l][2] = __expf(a.z); E[l][3] = __expf(a.w);
        E[l][4] = __expf(b.x); E[l][5] = __expf(b.y);
        E[l][6] = __expf(b.z); E[l][7] = __expf(b.w);
    }

    float f[8], g[8];
#pragma unroll
    for (int l = 0; l < 8; ++l) f[l] = 1.0f;

    for (int it = 0; it < ITERS; ++it) {
        // ---------- column pass: g = 1 / (E^T f) ----------
        float p[8];
#pragma unroll
        for (int k = 0; k < 8; ++k) p[k] = E[0][k] * f[0];
#pragma unroll
        for (int l = 1; l < 8; ++l)
#pragma unroll
            for (int k = 0; k < 8; ++k) p[k] += E[l][k] * f[l];
        // combine the wave's two tile-rows (lane ^ 32 holds same columns, other row)
#pragma unroll
        for (int k = 0; k < 8; ++k) p[k] += __shfl_xor(p[k], 32, 64);
        if ((t & 32) == 0) {
            // swizzled write: 32 lanes -> 32 distinct banks
#pragma unroll
            for (int k = 0; k < 8; ++k)
                part[w][col0 + ((k + rot) & 7)] = p[k];
        }
        __syncthreads();
        if (t < MAT_N) {
            const int pos = (t & ~7) | (((t & 7) + (t >> 5)) & 7);  // swizzle inverse
            float s = 0.0f;
#pragma unroll
            for (int r = 0; r < 16; ++r) s += part[r][pos];
            gvec[t] = 1.0f / s;
        }
        __syncthreads();

        {
            float4 g0 = *(const float4*)&gvec[col0];
            float4 g1 = *(const float4*)&gvec[col0 + 4];
            g[0] = g0.x; g[1] = g0.y; g[2] = g0.z; g[3] = g0.w;
            g[4] = g1.x; g[5] = g1.y; g[6] = g1.z; g[7] = g1.w;
        }

        // ---------- row pass: f = 1 / (E g), all in-wave ----------
        float q[8];
#pragma unroll
        for (int l = 0; l < 8; ++l) {
            float s = E[l][0] * g[0];
#pragma unroll
            for (int k = 1; k < 8; ++k) s += E[l][k] * g[k];
            q[l] = s;
        }
        // butterfly over lane bits 0..4 (tC): each 32-lane group owns one tile-row band
#pragma unroll
        for (int m = 1; m <= 16; m <<= 1)
#pragma unroll
            for (int l = 0; l < 8; ++l) q[l] += __shfl_xor(q[l], m, 64);
#pragma unroll
        for (int l = 0; l < 8; ++l) f[l] = 1.0f / q[l];
    }

    // ---------- output: out = E * f[row] * g[col] ----------
#pragma unroll
    for (int l = 0; l < 8; ++l) {
        float fr = f[l];
        float* rp = om + (row0 + l) * MAT_N + col0;
        *(float4*)(rp)     = make_float4(E[l][0] * fr * g[0], E[l][1] * fr * g[1],
                                         E[l][2] * fr * g[2], E[l][3] * fr * g[3]);
        *(float4*)(rp + 4) = make_float4(E[l][4] * fr * g[4], E[l][5] * fr * g[5],
                                         E[l][6] * fr * g[6], E[l][7] * fr * g[7]);
    }
}

extern "C" void kernel_launch(void* const* d_in, const int* in_sizes, int n_in,
                              void* d_out, int out_size, void* d_ws, size_t ws_size,
                              hipStream_t stream) {
    const float* x = (const float*)d_in[0];
    float* out = (float*)d_out;
    const int nmat = in_sizes[0] / (MAT_N * MAT_N);   // 512
    sinkhorn_kernel<<<nmat, TPB, 0, stream>>>(x, out);
}

// Round 3
// 364.748 us; speedup vs baseline: 1.2565x; 1.0041x over previous
//
#include <hip/hip_runtime.h>

#define MAT_N 256
#define TPB   1024
#define ITERS 20

// One block per 256x256 matrix; 1024 threads = 32x32 grid of 8x8 register tiles.
// Multiplicative-domain Sinkhorn: E = exp(x) held in VGPRs (64 regs/thread of data).
// amdgpu_waves_per_eu(4,4) pins the allocator to a 128-VGPR budget (4 waves/EU,
// 1 block/CU) so E is fully register-resident — without it the compiler targets
// 8 waves/EU (64 VGPR) and spills E to scratch (R2: ~150us of L2 spill traffic).
// Row pass: in-wave shuffle butterfly (f never leaves registers).
// Col pass: shfl_xor(32) pair-reduce -> 16 LDS partial rows (bank-swizzled) -> 2 barriers/iter.
__global__ __launch_bounds__(TPB)
__attribute__((amdgpu_waves_per_eu(4, 4)))
void sinkhorn_kernel(const float* __restrict__ x, float* __restrict__ out)
{
    const int t    = threadIdx.x;
    const int tR   = t >> 5;          // 0..31 tile row
    const int tC   = t & 31;          // 0..31 tile col
    const int row0 = tR << 3;
    const int col0 = tC << 3;
    const int w    = t >> 6;          // wave index 0..15
    const int rot  = (tC >> 2) & 7;   // bank-swizzle rotation for partial writes

    const float* __restrict__ xm = x   + (size_t)blockIdx.x * (MAT_N * MAT_N);
    float* __restrict__       om = out + (size_t)blockIdx.x * (MAT_N * MAT_N);

    __shared__ float part[16][MAT_N];   // pair-reduced column partials, swizzled
    __shared__ float gvec[MAT_N];

    // ---- load tile, E = exp(x) ----
    float E[8][8];
#pragma unroll
    for (int l = 0; l < 8; ++l) {
        const float* rp = xm + (row0 + l) * MAT_N + col0;
        float4 a = *(const float4*)(rp);
        float4 b = *(const float4*)(rp + 4);
        E[l][0] = __expf(a.x); E[l][1] = __expf(a.y);
        E[l][2] = __expf(a.z); E[l][3] = __expf(a.w);
        E[l][4] = __expf(b.x); E[l][5] = __expf(b.y);
        E[l][6] = __expf(b.z); E[l][7] = __expf(b.w);
    }

    float f[8], g[8];
#pragma unroll
    for (int l = 0; l < 8; ++l) f[l] = 1.0f;

    for (int it = 0; it < ITERS; ++it) {
        // ---------- column pass: g = 1 / (E^T f) ----------
        float p[8];
#pragma unroll
        for (int k = 0; k < 8; ++k) p[k] = E[0][k] * f[0];
#pragma unroll
        for (int l = 1; l < 8; ++l)
#pragma unroll
            for (int k = 0; k < 8; ++k) p[k] += E[l][k] * f[l];
        // combine the wave's two tile-rows (lane ^ 32 holds same columns, other row)
#pragma unroll
        for (int k = 0; k < 8; ++k) p[k] += __shfl_xor(p[k], 32, 64);
        if ((t & 32) == 0) {
            // swizzled write: 32 lanes -> 32 distinct banks
#pragma unroll
            for (int k = 0; k < 8; ++k)
                part[w][col0 + ((k + rot) & 7)] = p[k];
        }
        __syncthreads();
        if (t < MAT_N) {
            const int pos = (t & ~7) | (((t & 7) + (t >> 5)) & 7);  // swizzle inverse
            float s = 0.0f;
#pragma unroll
            for (int r = 0; r < 16; ++r) s += part[r][pos];
            gvec[t] = 1.0f / s;
        }
        __syncthreads();

        {
            float4 g0 = *(const float4*)&gvec[col0];
            float4 g1 = *(const float4*)&gvec[col0 + 4];
            g[0] = g0.x; g[1] = g0.y; g[2] = g0.z; g[3] = g0.w;
            g[4] = g1.x; g[5] = g1.y; g[6] = g1.z; g[7] = g1.w;
        }

        // ---------- row pass: f = 1 / (E g), all in-wave ----------
        float q[8];
#pragma unroll
        for (int l = 0; l < 8; ++l) {
            float s = E[l][0] * g[0];
#pragma unroll
            for (int k = 1; k < 8; ++k) s += E[l][k] * g[k];
            q[l] = s;
        }
        // butterfly over lane bits 0..4 (tC): each 32-lane group owns one tile-row band
#pragma unroll
        for (int m = 1; m <= 16; m <<= 1)
#pragma unroll
            for (int l = 0; l < 8; ++l) q[l] += __shfl_xor(q[l], m, 64);
#pragma unroll
        for (int l = 0; l < 8; ++l) f[l] = 1.0f / q[l];
    }

    // ---------- output: out = E * f[row] * g[col] ----------
#pragma unroll
    for (int l = 0; l < 8; ++l) {
        float fr = f[l];
        float* rp = om + (row0 + l) * MAT_N + col0;
        *(float4*)(rp)     = make_float4(E[l][0] * fr * g[0], E[l][1] * fr * g[1],
                                         E[l][2] * fr * g[2], E[l][3] * fr * g[3]);
        *(float4*)(rp + 4) = make_float4(E[l][4] * fr * g[4], E[l][5] * fr * g[5],
                                         E[l][6] * fr * g[6], E[l][7] * fr * g[7]);
    }
}

extern "C" void kernel_launch(void* const* d_in, const int* in_sizes, int n_in,
                              void* d_out, int out_size, void* d_ws, size_t ws_size,
                              hipStream_t stream) {
    const float* x = (const float*)d_in[0];
    float* out = (float*)d_out;
    const int nmat = in_sizes[0] / (MAT_N * MAT_N);   // 512
    sinkhorn_kernel<<<nmat, TPB, 0, stream>>>(x, out);
}